// Round 17
// baseline (98.508 us; speedup 1.0000x reference)
//
#include <hip/hip_runtime.h>
#include <math.h>

// NaiveDFTQNN: 25-wire state vector, DIM = 2^25.
// out = (cos(theta[0]/2)/||f||) * (tensor product of 12 Givens rotations) * f
// Pair j (j=0..11) acts on little-endian element bits (2j+1, 2j), angle theta[11-j]/2:
//   v=01: n01 = c*a01 - s*a10 ; v=10: n10 = s*a01 + c*a10 ; v=00,11 untouched.
// Bit 24 (wire 0) is a spectator (RX folds into the scalar).
//
// Ledger (A/B r6..r16): `in` NT-load; intermediate regular store + regular load;
// final NT-store (NT on the intermediate loses either direction). High granule:
// 128B->256B real gain (r14), 256B->512B null (r16) -> keep 256B. p1 must not
// couple its two register tiles before tile A's store phase (r15). p1 sumsq via
// fp32 pairwise tree (r12). r17: norm kernel eliminated — each high block
// redundantly reduces the 1024 partials (8 KB, IC-hot, deterministic identical
// order -> bit-identical scale in every block), overlapped with its 32 tile loads.

typedef float f32x4 __attribute__((ext_vector_type(4)));

static __device__ __forceinline__ float4 nt_load4(const float* p) {
    f32x4 v = __builtin_nontemporal_load((const f32x4*)p);
    return *(float4*)&v;
}
static __device__ __forceinline__ void nt_store4(float* p, float4 v) {
    __builtin_nontemporal_store(*(f32x4*)&v, (f32x4*)p);
}

// Barrier that drains ONLY lgkmcnt (LDS) — global loads/stores stay in flight.
static __device__ __forceinline__ void bar_lgkm() {
    asm volatile("s_waitcnt lgkmcnt(0)\n\ts_barrier" ::: "memory");
}

static __device__ __forceinline__ void rot4(float4& a, float4& b, float c, float s) {
    float4 na, nb;
    na.x = c*a.x - s*b.x;  nb.x = s*a.x + c*b.x;
    na.y = c*a.y - s*b.y;  nb.y = s*a.y + c*b.y;
    na.z = c*a.z - s*b.z;  nb.z = s*a.z + c*b.z;
    na.w = c*a.w - s*b.w;  nb.w = s*a.w + c*b.w;
    a = na; b = nb;
}

static __device__ __forceinline__ float4 shflx4(float4 v, int m) {
    float4 r;
    r.x = __shfl_xor(v.x, m, 64);
    r.y = __shfl_xor(v.y, m, 64);
    r.z = __shfl_xor(v.z, m, 64);
    r.w = __shfl_xor(v.w, m, 64);
    return r;
}

template <int NR>
static __device__ __forceinline__ void rotshfl(float4* f, int sh, float c, float s, int lane) {
    const int pv = (lane >> sh) & 3;
    const bool act = (pv == 1) || (pv == 2);
    const float cl = act ? c : 1.0f;
    const float sl = act ? ((pv == 1) ? -s : s) : 0.0f;
    const int m = 3 << sh;
#pragma unroll
    for (int k = 0; k < NR; ++k) {
        float4 p = shflx4(f[k], m);
        float4 n;
        n.x = fmaf(sl, p.x, cl * f[k].x);
        n.y = fmaf(sl, p.y, cl * f[k].y);
        n.z = fmaf(sl, p.z, cl * f[k].z);
        n.w = fmaf(sl, p.w, cl * f[k].w);
        f[k] = n;
    }
}

// fp32 pairwise-tree sum of squares over 16 float4 (64 values).
static __device__ __forceinline__ float sumsq16(const float4* f) {
    float q[16];
#pragma unroll
    for (int k = 0; k < 16; ++k)
        q[k] = fmaf(f[k].x, f[k].x,
               fmaf(f[k].y, f[k].y,
               fmaf(f[k].z, f[k].z, f[k].w * f[k].w)));
#pragma unroll
    for (int st = 1; st < 16; st <<= 1)
#pragma unroll
        for (int i = 0; i < 16; i += (st << 1))
            q[i] += q[i + st];
    return q[0];
}

// ---------------- qnn_p1: pairs j0..j6 (el bits 0..13), in -> out, + partials ------
// (r14 champion leg, verbatim: ~41 us, at the mixed-leg fabric ceiling)
// Tile = contiguous 4096 quads (s bits 0..11 = el bits 2..13); 2 tiles/block.
// Load layout  s = w2<<10 | k<<6 | lane: j0 components; j1/j2/j3 lane shfl
// (s 1,0/3,2/5,4); j4 = k(1,0); j5 = k(3,2).
// LDS exchange to s' = m<<8 | w2<<6 | lane: j6 = m(3,2). Store at s'.
__global__ __launch_bounds__(256, 2) void qnn_p1(const float* __restrict__ in,
                                                 const float* __restrict__ theta,
                                                 float* __restrict__ out,
                                                 double* __restrict__ partials) {
    __shared__ __align__(16) float4 lds[4096];   // 64 KB
    __shared__ double red[4];
    const int t = threadIdx.x, lane = t & 63, w2 = t >> 6;
    const long gA = (long)blockIdx.x << 13;      // quad base, tile A
    const long gB = gA + 4096;                   // tile B

    float c0,s0,c1,s1,c2,s2,c3,s3,c4,s4,c5,s5,c6,s6;
    { float th;
      th=0.5f*theta[11]; c0=cosf(th); s0=sinf(th);
      th=0.5f*theta[10]; c1=cosf(th); s1=sinf(th);
      th=0.5f*theta[9];  c2=cosf(th); s2=sinf(th);
      th=0.5f*theta[8];  c3=cosf(th); s3=sinf(th);
      th=0.5f*theta[7];  c4=cosf(th); s4=sinf(th);
      th=0.5f*theta[6];  c5=cosf(th); s5=sinf(th);
      th=0.5f*theta[5];  c6=cosf(th); s6=sinf(th); }

    float4 f[16], g[16];
#pragma unroll
    for (int k = 0; k < 16; ++k)
        f[k] = nt_load4(in + ((gA + ((w2 << 10) | (k << 6) | lane)) << 2));
#pragma unroll
    for (int k = 0; k < 16; ++k)
        g[k] = nt_load4(in + ((gB + ((w2 << 10) | (k << 6) | lane)) << 2));

    const float sA = sumsq16(f);

#pragma unroll
    for (int k = 0; k < 16; ++k) {
        float ny = c0*f[k].y - s0*f[k].z;
        float nz = s0*f[k].y + c0*f[k].z;
        f[k].y = ny; f[k].z = nz;
    }
    rotshfl<16>(f, 0, c1, s1, lane);
    rotshfl<16>(f, 2, c2, s2, lane);
    rotshfl<16>(f, 4, c3, s3, lane);
#pragma unroll
    for (int hi = 0; hi < 16; hi += 4) rot4(f[hi+1], f[hi+2], c4, s4);
#pragma unroll
    for (int lo = 0; lo < 4; ++lo)     rot4(f[4+lo], f[8+lo], c5, s5);

#pragma unroll
    for (int k = 0; k < 16; ++k) lds[(w2 << 10) | (k << 6) | lane] = f[k];
    bar_lgkm();
#pragma unroll
    for (int m = 0; m < 16; ++m) f[m] = lds[(m << 8) | (w2 << 6) | lane];
#pragma unroll
    for (int lo = 0; lo < 4; ++lo) rot4(f[4+lo], f[8+lo], c6, s6);
#pragma unroll
    for (int m = 0; m < 16; ++m)
        *(float4*)(out + ((gA + ((m << 8) | (w2 << 6) | lane)) << 2)) = f[m];

    const float sB = sumsq16(g);
#pragma unroll
    for (int k = 0; k < 16; ++k) {
        float ny = c0*g[k].y - s0*g[k].z;
        float nz = s0*g[k].y + c0*g[k].z;
        g[k].y = ny; g[k].z = nz;
    }
    rotshfl<16>(g, 0, c1, s1, lane);
    rotshfl<16>(g, 2, c2, s2, lane);
    rotshfl<16>(g, 4, c3, s3, lane);
#pragma unroll
    for (int hi = 0; hi < 16; hi += 4) rot4(g[hi+1], g[hi+2], c4, s4);
#pragma unroll
    for (int lo = 0; lo < 4; ++lo)     rot4(g[4+lo], g[8+lo], c5, s5);

    bar_lgkm();
#pragma unroll
    for (int k = 0; k < 16; ++k) lds[(w2 << 10) | (k << 6) | lane] = g[k];
    bar_lgkm();
#pragma unroll
    for (int m = 0; m < 16; ++m) g[m] = lds[(m << 8) | (w2 << 6) | lane];
#pragma unroll
    for (int lo = 0; lo < 4; ++lo) rot4(g[4+lo], g[8+lo], c6, s6);
#pragma unroll
    for (int m = 0; m < 16; ++m)
        *(float4*)(out + ((gB + ((m << 8) | (w2 << 6) | lane)) << 2)) = g[m];

    double acc = (double)sA + (double)sB;
#pragma unroll
    for (int off = 32; off > 0; off >>= 1) acc += __shfl_down(acc, off, 64);
    if (lane == 0) red[w2] = acc;
    bar_lgkm();
    if (t == 0)
        partials[blockIdx.x] = red[0] + red[1] + red[2] + red[3];
}

// ---------------- qnn_high: pairs j7..j11 (el bits 14..23) + scale, in place -------
// (r14 champion structure: 256 B granules; + inlined norm reduce)
// Tile slot s (13 bits) = H<<4 | pq; H = el bits 14..22 (9 bits), pq = el 2..5.
// Global quad = b24<<22 | b23<<21 | (s>>4)<<12 | mid<<4 | (s&15);
// grid bid = b24<<8 | mid (512 blocks); block holds BOTH b23 tiles (f,g).
// Load s = k<<9 | t: j7 = s(5,4) lane shfl sh=4; j10 = s(11,10) = k(2,1);
// j11 = (b23, k3) -> rot4(f[8+i], g[i]).
// Read s' = (t>>6)<<10 | m<<6 | (t&63): j8 = m(1,0); j9 = m(3,2).
// Regular loads (IC-resident), NT final stores, lgkm-only barriers.
__global__ __launch_bounds__(512, 2) void qnn_high(float* __restrict__ buf,
                                                   const float* __restrict__ theta,
                                                   const double* __restrict__ partials) {
    __shared__ __align__(16) float4 lds[8192];   // 128 KB
    const int t = threadIdx.x, lane = t & 63;
    const int bid = blockIdx.x;
    const int b24 = bid >> 8, mid = bid & 255;
    const long baseA = ((long)b24 << 22) | ((long)mid << 4);   // b23 = 0
    const long baseB = baseA | (1L << 21);                     // b23 = 1

    float c7,s7,c8,s8,c9,s9,c10,s10,c11,s11;
    { float th;
      th=0.5f*theta[4]; c7 =cosf(th); s7 =sinf(th);
      th=0.5f*theta[3]; c8 =cosf(th); s8 =sinf(th);
      th=0.5f*theta[2]; c9 =cosf(th); s9 =sinf(th);
      th=0.5f*theta[1]; c10=cosf(th); s10=sinf(th);
      th=0.5f*theta[0]; c11=cosf(th); s11=sinf(th); }

    float4 f[16], g[16];
    // ---- issue ALL 32 tile loads first (reduce below overlaps their latency) ----
#pragma unroll
    for (int k = 0; k < 16; ++k) {
        const int s_ = (k << 9) | t;
        f[k] = *(const float4*)(buf + ((baseA | ((long)(s_ >> 4) << 12) | (s_ & 15)) << 2));
    }
#pragma unroll
    for (int k = 0; k < 16; ++k) {
        const int s_ = (k << 9) | t;
        g[k] = *(const float4*)(buf + ((baseB | ((long)(s_ >> 4) << 12) | (s_ & 15)) << 2));
    }

    // ---- inlined norm: every block reduces the 1024 partials identically ----
    // (deterministic fixed order -> bit-identical scale in all blocks)
    double acc = partials[t] + partials[t + 512];
#pragma unroll
    for (int off = 32; off > 0; off >>= 1) acc += __shfl_down(acc, off, 64);
    {
        double* dl = (double*)lds;           // 8 doubles of scratch, pre-tile use
        if (lane == 0) dl[t >> 6] = acc;
        bar_lgkm();
        double tot = dl[0] + dl[1] + dl[2] + dl[3] + dl[4] + dl[5] + dl[6] + dl[7];
        acc = (double)cosf(0.5f * theta[0]) / sqrt(tot);
        bar_lgkm();                          // all reads of dl done before tile writes
    }
    const float sc = (float)acc;

    // ---- register rotations: j7 (shfl), j10 (k regs), j11 (cross f/g) ----
    rotshfl<16>(f, 4, c7, s7, lane);
    rotshfl<16>(g, 4, c7, s7, lane);
#pragma unroll
    for (int h8 = 0; h8 < 16; h8 += 8) {           // j10: k bits 2,1
        rot4(f[h8+2], f[h8+4], c10, s10);
        rot4(f[h8+3], f[h8+5], c10, s10);
        rot4(g[h8+2], g[h8+4], c10, s10);
        rot4(g[h8+3], g[h8+5], c10, s10);
    }
#pragma unroll
    for (int i = 0; i < 8; ++i)                    // j11: (b23, k bit 3)
        rot4(f[8+i], g[i], c11, s11);

    // ---- tile A (b23=0): LDS trip for j8/j9, scale, NT store ----
#pragma unroll
    for (int k = 0; k < 16; ++k) lds[(k << 9) | t] = f[k];
    bar_lgkm();
    {
        const int rb = ((t >> 6) << 10) | (t & 63);
#pragma unroll
        for (int m = 0; m < 16; ++m) f[m] = lds[rb | (m << 6)];
#pragma unroll
        for (int q = 0; q < 16; q += 4) rot4(f[q+1], f[q+2], c8, s8);   // j8
#pragma unroll
        for (int lo = 0; lo < 4; ++lo)  rot4(f[4+lo], f[8+lo], c9, s9); // j9
#pragma unroll
        for (int m = 0; m < 16; ++m) {
            const int s_ = rb | (m << 6);
            float4 v = f[m];
            v.x *= sc; v.y *= sc; v.z *= sc; v.w *= sc;
            nt_store4(buf + ((baseA | ((long)(s_ >> 4) << 12) | (s_ & 15)) << 2), v);
        }
    }
    bar_lgkm();   // all waves done reading A's LDS image

    // ---- tile B (b23=1) ----
#pragma unroll
    for (int k = 0; k < 16; ++k) lds[(k << 9) | t] = g[k];
    bar_lgkm();
    {
        const int rb = ((t >> 6) << 10) | (t & 63);
#pragma unroll
        for (int m = 0; m < 16; ++m) g[m] = lds[rb | (m << 6)];
#pragma unroll
        for (int q = 0; q < 16; q += 4) rot4(g[q+1], g[q+2], c8, s8);   // j8
#pragma unroll
        for (int lo = 0; lo < 4; ++lo)  rot4(g[4+lo], g[8+lo], c9, s9); // j9
#pragma unroll
        for (int m = 0; m < 16; ++m) {
            const int s_ = rb | (m << 6);
            float4 v = g[m];
            v.x *= sc; v.y *= sc; v.z *= sc; v.w *= sc;
            nt_store4(buf + ((baseB | ((long)(s_ >> 4) << 12) | (s_ & 15)) << 2), v);
        }
    }
}

extern "C" void kernel_launch(void* const* d_in, const int* in_sizes, int n_in,
                              void* d_out, int out_size, void* d_ws, size_t ws_size,
                              hipStream_t stream) {
    const float* in = (const float*)d_in[0];      // feature, 2^25 f32
    const float* theta = (const float*)d_in[1];   // 13 f32
    float* out = (float*)d_out;                   // 2^25 f32
    double* part = (double*)d_ws;                 // 1024 partials

    qnn_p1<<<1024, 256, 0, stream>>>(in, theta, out, part);
    qnn_high<<<512, 512, 0, stream>>>(out, theta, part);
}

// Round 18
// 93.438 us; speedup vs baseline: 1.0543x; 1.0543x over previous
//
#include <hip/hip_runtime.h>
#include <math.h>

// NaiveDFTQNN: 25-wire state vector, DIM = 2^25.
// out = (cos(theta[0]/2)/||f||) * (tensor product of 12 Givens rotations) * f
// Pair j (j=0..11) acts on little-endian element bits (2j+1, 2j), angle theta[11-j]/2:
//   v=01: n01 = c*a01 - s*a10 ; v=10: n10 = s*a01 + c*a10 ; v=00,11 untouched.
// Bit 24 (wire 0) is a spectator (RX folds into the scalar).
//
// CHAMPION (r14, 93.6 us). Final experiment ledger:
//   - `in` NT-load; intermediate regular store + regular load; final NT-store
//     (NT on the intermediate loses either direction — r11/r12 A/B).
//   - p1: 256 thr x 16 quads x 2 tiles, ALL 32 loads upfront (MLP-limited —
//     r10: higher occupancy with shallower MLP was -32 us), 64 KB LDS, 1 LDS
//     trip/tile, lgkm-only barriers, fp32 pairwise sumsq (r12: -15 us).
//     Runs ~41 us = ~6.2 TB/s, at the mixed-leg fabric ceiling.
//   - high: 256 B granules (r14: +4 us vs 128 B; r16: 512 B null), j11 via
//     cross-register-tile rot (b23 pairing), zero extra LDS trips.
//   - norm as separate 2 us dispatch (r17: fusing it into high was -5 us).
// Gap to structural floor (512 MB @ 6.3 TB/s + launch overhead ~= 87 us) < 7%.

typedef float f32x4 __attribute__((ext_vector_type(4)));

static __device__ __forceinline__ float4 nt_load4(const float* p) {
    f32x4 v = __builtin_nontemporal_load((const f32x4*)p);
    return *(float4*)&v;
}
static __device__ __forceinline__ void nt_store4(float* p, float4 v) {
    __builtin_nontemporal_store(*(f32x4*)&v, (f32x4*)p);
}

// Barrier that drains ONLY lgkmcnt (LDS) — global loads/stores stay in flight.
static __device__ __forceinline__ void bar_lgkm() {
    asm volatile("s_waitcnt lgkmcnt(0)\n\ts_barrier" ::: "memory");
}

static __device__ __forceinline__ void rot4(float4& a, float4& b, float c, float s) {
    float4 na, nb;
    na.x = c*a.x - s*b.x;  nb.x = s*a.x + c*b.x;
    na.y = c*a.y - s*b.y;  nb.y = s*a.y + c*b.y;
    na.z = c*a.z - s*b.z;  nb.z = s*a.z + c*b.z;
    na.w = c*a.w - s*b.w;  nb.w = s*a.w + c*b.w;
    a = na; b = nb;
}

static __device__ __forceinline__ float4 shflx4(float4 v, int m) {
    float4 r;
    r.x = __shfl_xor(v.x, m, 64);
    r.y = __shfl_xor(v.y, m, 64);
    r.z = __shfl_xor(v.z, m, 64);
    r.w = __shfl_xor(v.w, m, 64);
    return r;
}

template <int NR>
static __device__ __forceinline__ void rotshfl(float4* f, int sh, float c, float s, int lane) {
    const int pv = (lane >> sh) & 3;
    const bool act = (pv == 1) || (pv == 2);
    const float cl = act ? c : 1.0f;
    const float sl = act ? ((pv == 1) ? -s : s) : 0.0f;
    const int m = 3 << sh;
#pragma unroll
    for (int k = 0; k < NR; ++k) {
        float4 p = shflx4(f[k], m);
        float4 n;
        n.x = fmaf(sl, p.x, cl * f[k].x);
        n.y = fmaf(sl, p.y, cl * f[k].y);
        n.z = fmaf(sl, p.z, cl * f[k].z);
        n.w = fmaf(sl, p.w, cl * f[k].w);
        f[k] = n;
    }
}

// fp32 pairwise-tree sum of squares over 16 float4 (64 values).
static __device__ __forceinline__ float sumsq16(const float4* f) {
    float q[16];
#pragma unroll
    for (int k = 0; k < 16; ++k)
        q[k] = fmaf(f[k].x, f[k].x,
               fmaf(f[k].y, f[k].y,
               fmaf(f[k].z, f[k].z, f[k].w * f[k].w)));
#pragma unroll
    for (int st = 1; st < 16; st <<= 1)
#pragma unroll
        for (int i = 0; i < 16; i += (st << 1))
            q[i] += q[i + st];
    return q[0];
}

// ---------------- qnn_p1: pairs j0..j6 (el bits 0..13), in -> out, + partials ------
// Tile = contiguous 4096 quads (s bits 0..11 = el bits 2..13); 2 tiles/block.
// Load layout  s = w2<<10 | k<<6 | lane: j0 components; j1/j2/j3 lane shfl
// (s 1,0/3,2/5,4); j4 = k(1,0); j5 = k(3,2).
// LDS exchange to s' = m<<8 | w2<<6 | lane: j6 = m(3,2). Store at s'.
__global__ __launch_bounds__(256, 2) void qnn_p1(const float* __restrict__ in,
                                                 const float* __restrict__ theta,
                                                 float* __restrict__ out,
                                                 double* __restrict__ partials) {
    __shared__ __align__(16) float4 lds[4096];   // 64 KB
    __shared__ double red[4];
    const int t = threadIdx.x, lane = t & 63, w2 = t >> 6;
    const long gA = (long)blockIdx.x << 13;      // quad base, tile A
    const long gB = gA + 4096;                   // tile B

    float c0,s0,c1,s1,c2,s2,c3,s3,c4,s4,c5,s5,c6,s6;
    { float th;
      th=0.5f*theta[11]; c0=cosf(th); s0=sinf(th);
      th=0.5f*theta[10]; c1=cosf(th); s1=sinf(th);
      th=0.5f*theta[9];  c2=cosf(th); s2=sinf(th);
      th=0.5f*theta[8];  c3=cosf(th); s3=sinf(th);
      th=0.5f*theta[7];  c4=cosf(th); s4=sinf(th);
      th=0.5f*theta[6];  c5=cosf(th); s5=sinf(th);
      th=0.5f*theta[5];  c6=cosf(th); s6=sinf(th); }

    float4 f[16], g[16];
    // ---- issue ALL 32 loads (B's stay in flight deep into A's processing) ----
#pragma unroll
    for (int k = 0; k < 16; ++k)
        f[k] = nt_load4(in + ((gA + ((w2 << 10) | (k << 6) | lane)) << 2));
#pragma unroll
    for (int k = 0; k < 16; ++k)
        g[k] = nt_load4(in + ((gB + ((w2 << 10) | (k << 6) | lane)) << 2));

    const float sA = sumsq16(f);

#pragma unroll
    for (int k = 0; k < 16; ++k) {
        float ny = c0*f[k].y - s0*f[k].z;
        float nz = s0*f[k].y + c0*f[k].z;
        f[k].y = ny; f[k].z = nz;
    }
    rotshfl<16>(f, 0, c1, s1, lane);
    rotshfl<16>(f, 2, c2, s2, lane);
    rotshfl<16>(f, 4, c3, s3, lane);
#pragma unroll
    for (int hi = 0; hi < 16; hi += 4) rot4(f[hi+1], f[hi+2], c4, s4);
#pragma unroll
    for (int lo = 0; lo < 4; ++lo)     rot4(f[4+lo], f[8+lo], c5, s5);

#pragma unroll
    for (int k = 0; k < 16; ++k) lds[(w2 << 10) | (k << 6) | lane] = f[k];
    bar_lgkm();
#pragma unroll
    for (int m = 0; m < 16; ++m) f[m] = lds[(m << 8) | (w2 << 6) | lane];
#pragma unroll
    for (int lo = 0; lo < 4; ++lo) rot4(f[4+lo], f[8+lo], c6, s6);
#pragma unroll
    for (int m = 0; m < 16; ++m)
        *(float4*)(out + ((gA + ((m << 8) | (w2 << 6) | lane)) << 2)) = f[m];

    const float sB = sumsq16(g);
#pragma unroll
    for (int k = 0; k < 16; ++k) {
        float ny = c0*g[k].y - s0*g[k].z;
        float nz = s0*g[k].y + c0*g[k].z;
        g[k].y = ny; g[k].z = nz;
    }
    rotshfl<16>(g, 0, c1, s1, lane);
    rotshfl<16>(g, 2, c2, s2, lane);
    rotshfl<16>(g, 4, c3, s3, lane);
#pragma unroll
    for (int hi = 0; hi < 16; hi += 4) rot4(g[hi+1], g[hi+2], c4, s4);
#pragma unroll
    for (int lo = 0; lo < 4; ++lo)     rot4(g[4+lo], g[8+lo], c5, s5);

    bar_lgkm();   // all waves done reading A's LDS image
#pragma unroll
    for (int k = 0; k < 16; ++k) lds[(w2 << 10) | (k << 6) | lane] = g[k];
    bar_lgkm();
#pragma unroll
    for (int m = 0; m < 16; ++m) g[m] = lds[(m << 8) | (w2 << 6) | lane];
#pragma unroll
    for (int lo = 0; lo < 4; ++lo) rot4(g[4+lo], g[8+lo], c6, s6);
#pragma unroll
    for (int m = 0; m < 16; ++m)
        *(float4*)(out + ((gB + ((m << 8) | (w2 << 6) | lane)) << 2)) = g[m];

    double acc = (double)sA + (double)sB;
#pragma unroll
    for (int off = 32; off > 0; off >>= 1) acc += __shfl_down(acc, off, 64);
    if (lane == 0) red[w2] = acc;
    bar_lgkm();
    if (t == 0)
        partials[blockIdx.x] = red[0] + red[1] + red[2] + red[3];
}

// ---------------- Norm: 1024 partials -> scale = cos(theta[0]/2)/sqrt(sum) ---------
__global__ void qnn_norm(const double* __restrict__ partials,
                         const float* __restrict__ theta,
                         double* __restrict__ scale) {
    __shared__ double w[4];
    const int t = threadIdx.x;
    double acc = 0.0;
    for (int i = t; i < 1024; i += 256) acc += partials[i];
#pragma unroll
    for (int off = 32; off > 0; off >>= 1) acc += __shfl_down(acc, off, 64);
    if ((t & 63) == 0) w[t >> 6] = acc;
    __syncthreads();
    if (t == 0) {
        double tot = w[0] + w[1] + w[2] + w[3];
        *scale = (double)cosf(0.5f * theta[0]) / sqrt(tot);
    }
}

// ---------------- qnn_high: pairs j7..j11 (el bits 14..23) + scale, in place -------
// 256 B granules. Tile slot s (13 bits) = H<<4 | pq; H = el bits 14..22
// (9 bits), pq = el bits 2..5 (16 quads contiguous = 256 B granule).
// Global quad = b24<<22 | b23<<21 | (s>>4)<<12 | mid<<4 | (s&15);
// grid bid = b24<<8 | mid (512 blocks); block holds BOTH b23 tiles in regs
// (f = b23:0, g = b23:1), 16 quads each (512 thr).
// Load layout s = k<<9 | t: j7 = s(5,4) = lane shfl sh=4; j10 = s(11,10) =
// k(2,1) -> (f2,f4),(f3,f5),(f10,f12),(f11,f13); j11 = (b23, s12=k3) ->
// rot4(f[8+i], g[i]).
// Read layout s' = (t>>6)<<10 | m<<6 | (t&63): j8 = s(7,6) = m(1,0) ->
// rot4(r[4q+1],r[4q+2]); j9 = s(9,8) = m(3,2) -> rot4(r[4+lo],r[8+lo]).
// Regular loads (IC-resident intermediate), NT final stores. 3 lgkm barriers.
__global__ __launch_bounds__(512, 2) void qnn_high(float* __restrict__ buf,
                                                   const float* __restrict__ theta,
                                                   const double* __restrict__ scale) {
    __shared__ __align__(16) float4 lds[8192];   // 128 KB
    const int t = threadIdx.x, lane = t & 63;
    const int bid = blockIdx.x;
    const int b24 = bid >> 8, mid = bid & 255;
    const long baseA = ((long)b24 << 22) | ((long)mid << 4);   // b23 = 0
    const long baseB = baseA | (1L << 21);                     // b23 = 1

    float c7,s7,c8,s8,c9,s9,c10,s10,c11,s11;
    { float th;
      th=0.5f*theta[4]; c7 =cosf(th); s7 =sinf(th);
      th=0.5f*theta[3]; c8 =cosf(th); s8 =sinf(th);
      th=0.5f*theta[2]; c9 =cosf(th); s9 =sinf(th);
      th=0.5f*theta[1]; c10=cosf(th); s10=sinf(th);
      th=0.5f*theta[0]; c11=cosf(th); s11=sinf(th); }
    const float sc = (float)(*scale);

    float4 f[16], g[16];
    // ---- issue ALL 32 loads (regular; 256 B granules at 64 KB stride) ----
#pragma unroll
    for (int k = 0; k < 16; ++k) {
        const int s_ = (k << 9) | t;
        f[k] = *(const float4*)(buf + ((baseA | ((long)(s_ >> 4) << 12) | (s_ & 15)) << 2));
    }
#pragma unroll
    for (int k = 0; k < 16; ++k) {
        const int s_ = (k << 9) | t;
        g[k] = *(const float4*)(buf + ((baseB | ((long)(s_ >> 4) << 12) | (s_ & 15)) << 2));
    }

    // ---- register rotations: j7 (shfl), j10 (k regs), j11 (cross f/g) ----
    rotshfl<16>(f, 4, c7, s7, lane);
    rotshfl<16>(g, 4, c7, s7, lane);
#pragma unroll
    for (int h8 = 0; h8 < 16; h8 += 8) {           // j10: k bits 2,1
        rot4(f[h8+2], f[h8+4], c10, s10);
        rot4(f[h8+3], f[h8+5], c10, s10);
        rot4(g[h8+2], g[h8+4], c10, s10);
        rot4(g[h8+3], g[h8+5], c10, s10);
    }
#pragma unroll
    for (int i = 0; i < 8; ++i)                    // j11: (b23, k bit 3)
        rot4(f[8+i], g[i], c11, s11);

    // ---- tile A (b23=0): LDS trip for j8/j9, scale, NT store ----
#pragma unroll
    for (int k = 0; k < 16; ++k) lds[(k << 9) | t] = f[k];
    bar_lgkm();
    {
        const int rb = ((t >> 6) << 10) | (t & 63);
#pragma unroll
        for (int m = 0; m < 16; ++m) f[m] = lds[rb | (m << 6)];
#pragma unroll
        for (int q = 0; q < 16; q += 4) rot4(f[q+1], f[q+2], c8, s8);   // j8
#pragma unroll
        for (int lo = 0; lo < 4; ++lo)  rot4(f[4+lo], f[8+lo], c9, s9); // j9
#pragma unroll
        for (int m = 0; m < 16; ++m) {
            const int s_ = rb | (m << 6);
            float4 v = f[m];
            v.x *= sc; v.y *= sc; v.z *= sc; v.w *= sc;
            nt_store4(buf + ((baseA | ((long)(s_ >> 4) << 12) | (s_ & 15)) << 2), v);
        }
    }
    bar_lgkm();   // all waves done reading A's LDS image

    // ---- tile B (b23=1) ----
#pragma unroll
    for (int k = 0; k < 16; ++k) lds[(k << 9) | t] = g[k];
    bar_lgkm();
    {
        const int rb = ((t >> 6) << 10) | (t & 63);
#pragma unroll
        for (int m = 0; m < 16; ++m) g[m] = lds[rb | (m << 6)];
#pragma unroll
        for (int q = 0; q < 16; q += 4) rot4(g[q+1], g[q+2], c8, s8);   // j8
#pragma unroll
        for (int lo = 0; lo < 4; ++lo)  rot4(g[4+lo], g[8+lo], c9, s9); // j9
#pragma unroll
        for (int m = 0; m < 16; ++m) {
            const int s_ = rb | (m << 6);
            float4 v = g[m];
            v.x *= sc; v.y *= sc; v.z *= sc; v.w *= sc;
            nt_store4(buf + ((baseB | ((long)(s_ >> 4) << 12) | (s_ & 15)) << 2), v);
        }
    }
}

extern "C" void kernel_launch(void* const* d_in, const int* in_sizes, int n_in,
                              void* d_out, int out_size, void* d_ws, size_t ws_size,
                              hipStream_t stream) {
    const float* in = (const float*)d_in[0];      // feature, 2^25 f32
    const float* theta = (const float*)d_in[1];   // 13 f32
    float* out = (float*)d_out;                   // 2^25 f32
    double* part = (double*)d_ws;                 // 1024 partials + 1 scale
    double* scale = part + 1024;

    qnn_p1<<<1024, 256, 0, stream>>>(in, theta, out, part);
    qnn_norm<<<1, 256, 0, stream>>>(part, theta, scale);
    qnn_high<<<512, 512, 0, stream>>>(out, theta, scale);
}